// Round 7
// baseline (165.705 us; speedup 1.0000x reference)
//
#include <hip/hip_runtime.h>

// SSIM loss v14: half-strip pairing -> 2 cols/lane AT CH_H=64.
// v13 evidence: 2-col sharing cut per-output cost 730->686 cyc, but CH_H=32
// (forced by wave-count arithmetic at 128 cols/wave) added +13.5% halo work.
// v14 construction: one wave = TWO independent 64-col half-strips (lanes
// 0-31 strip 2t, lanes 32-63 strip 2t+1; same chunk+plane -> row offset
// stays wave-uniform). All 64 lanes active, 2 cols/lane, CH_H=64 restored:
// 1536 waves x 74 steps = 113,664 wave-steps (-11.9% vs v13). Launched as
// 1536 single-wave blocks = exactly 6/CU, balanced; no syncthreads at all.
// Occupancy gamble: 1.5 waves/SIMD (v9 proved >=3 saturates; below 3 is
// THE question this round answers). Also: v10's verified fresh-slot product
// fold (10-slot ring, -6 inst/step).
// Predicted: VALUBusy ~55-62% (win) or ~40% (occupancy collapse);
// kernel 72.4 -> 62-65us on success; WRITE_SIZE ~24KB (spill tripwire).

#define BATCH  16
#define CHAN   3
#define H_     512
#define W_     512
#define HW     (H_ * W_)
#define CH_H   64
#define NSTEP  (CH_H + 10)          // 74
#define NPIX   ((long)BATCH*CHAN*H_*W_)

// Normalized 11-tap Gaussian, sigma=1.5 (constants gave absmax 0 in v1/v2/v6).
#define GW0 0.0010284f
#define GW1 0.0075988f
#define GW2 0.0360008f
#define GW3 0.1093554f
#define GW4 0.2130056f
#define GW5 0.2660117f

typedef float v2  __attribute__((ext_vector_type(2)));
typedef float v4f __attribute__((ext_vector_type(4)));

__device__ __forceinline__ float wg(int k) {  // k literal -> folds to constant
    return (k == 0 || k == 10) ? GW0
         : (k == 1 || k == 9)  ? GW1
         : (k == 2 || k == 8)  ? GW2
         : (k == 3 || k == 7)  ? GW3
         : (k == 4 || k == 6)  ? GW4 : GW5;
}

__device__ __forceinline__ v2 pfma(v2 a, v2 b, v2 c) {
#if __has_builtin(__builtin_elementwise_fma)
    return __builtin_elementwise_fma(a, b, c);
#else
    v2 r; r.x = fmaf(a.x, b.x, c.x); r.y = fmaf(a.y, b.y, c.y); return r;
#endif
}
__device__ __forceinline__ v2 psfma(float s, v2 b, v2 c) {  // (s,s)*b + c
    v2 sv; sv.x = s; sv.y = s;
    return pfma(sv, b, c);
}

__device__ __forceinline__ float ssim_retire(float mu1, float mu2,
                                             float x11, float x22, float x12) {
    const float c1 = 1.0e-4f;
    const float c2 = 9.0e-4f;
    float mu1s = mu1 * mu1;
    float mu2s = mu2 * mu2;
    float m12  = mu1 * mu2;
    float num  = (2.0f * m12 + c1) * (2.0f * (x12 - m12) + c2);
    float den  = (mu1s + mu2s + c1) * ((x11 - mu1s) + (x22 - mu2s) + c2);
#if __has_builtin(__builtin_amdgcn_rcpf)
    float l = 1.0f - num * __builtin_amdgcn_rcpf(den);   // v_rcp_f32, ~1 ulp
#else
    float l = 1.0f - num / den;
#endif
    return fminf(fmaxf(l, 0.0f), 1.0f);
}

// 10-slot ring, two columns A/B per lane. Fresh slot enters as a direct
// product (v10's verified fold), so no slot-10 zero-init.
#define DECL(i) v2 PA##i = {0.f,0.f}, QA##i = {0.f,0.f}, PB##i = {0.f,0.f}, \
                   QB##i = {0.f,0.f}; float EA##i = 0.f, EB##i = 0.f
#define ACCI(i) do { const float wj_ = wg(10 - (i));             \
    PA##i = psfma(wj_, hmmA, PA##i);                             \
    QA##i = psfma(wj_, hssA, QA##i);                             \
    EA##i = fmaf(wj_, hm12A, EA##i);                             \
    PB##i = psfma(wj_, hmmB, PB##i);                             \
    QB##i = psfma(wj_, hssB, QB##i);                             \
    EB##i = fmaf(wj_, hm12B, EB##i); } while (0)
#define SHIFT(i, j) PA##i = PA##j; QA##i = QA##j; EA##i = EA##j; \
                    PB##i = PB##j; QB##i = QB##j; EB##i = EB##j

#define HT_A(ab_, k_) { v2 t = (ab_) * wg(k_); hmmA += t; \
    hssA = pfma(t, (ab_), hssA); hm12A = fmaf(t.x, (ab_).y, hm12A); }
#define HT_B(ab_, k_) { v2 t = (ab_) * wg(k_); hmmB += t; \
    hssB = pfma(t, (ab_), hssB); hm12B = fmaf(t.x, (ab_).y, hm12B); }

// Branchless padded-row load (row uniform across the wave).
#define LOADROW(r_) do {                                           \
    int rr_ = (r_);                                                \
    bool rok_ = (unsigned)rr_ < (unsigned)H_;                      \
    size_t off_ = ((size_t)(rok_ ? rr_ : 0) << 9);                 \
    float mm_ = rok_ ? msk  : 0.0f;                                \
    float hm_ = rok_ ? hmsk : 0.0f;                                \
    ma = *(const v2*)(p1 + off_ + cix) * mm_;                      \
    mb = *(const v2*)(p2 + off_ + cix) * mm_;                      \
    ha = *(const v2*)(p1 + off_ + hix) * hm_;                      \
    hb = *(const v2*)(p2 + off_ + hix) * hm_; } while (0)

__global__ __launch_bounds__(64) void ssim_kernel(const float* __restrict__ img1,
                                                  const float* __restrict__ img2,
                                                  float* __restrict__ out) {
    // One wave per block. Two 80-entry half-buffers (one per half-strip);
    // entry e of half h <-> global col (c0h - 6 + e), interleaved (img1,img2).
    __shared__ __align__(16) v2 sp[2][80];   // 75 entries used (+1 pad write)

    const int lane = threadIdx.x & 63;
    const int half = lane >> 5;                // which half-strip
    const int l    = lane & 31;                // lane within half

    const int wid   = blockIdx.x;              // 0..1535
    const int plane = wid >> 5;                // 48 planes
    const int rem   = wid & 31;
    const int t     = rem & 3;                 // 128-col strip pair, 0..3
    const int chunk = rem >> 2;                // 0..7
    const int y0  = chunk * CH_H;
    const int c0h = t * 128 + half * 64;       // this half's first output col

    // Main: lane (h,l) owns col pair (c0h-6+2l, +1); whole pair in/out
    // together (left edge only: t=0,half=0,l<3). Max col 504+1 -> in range.
    const int  cg   = c0h - 6 + 2 * l;
    const bool cok  = (cg >= 0);
    const int  cix  = cok ? cg : 0;
    const float msk = cok ? 1.0f : 0.0f;
    // Halo: lanes l<6 own col pair (c0h+58+2l, +1); right edge only.
    const int  hg   = c0h + 58 + 2 * l;
    const bool hok  = (l < 6) && (hg + 1 < W_);
    const int  hix  = hok ? hg : 0;
    const float hmsk = hok ? 1.0f : 0.0f;

    const size_t pb = (size_t)plane * HW;
    const float* __restrict__ p1 = img1 + pb;   // wave-uniform bases
    const float* __restrict__ p2 = img2 + pb;

    v2* st = sp[half];

    DECL(0); DECL(1); DECL(2); DECL(3); DECL(4);
    DECL(5); DECL(6); DECL(7); DECL(8); DECL(9);
    float lsum = 0.0f;

    // Preload first h-row (r = y0 - 5; zero if OOB -> matches zero padding).
    v2 ma, mb, ha, hb;
    LOADROW(y0 - 5);

#pragma unroll 2
    for (int step = 0; step < NSTEP; ++step) {
        const int yy = step - 10;              // output row retired this step

        // 1. Stage current h-row: main pair as one ds_write_b128 (entries
        //    2l,2l+1), halo pairs by lanes l<6 (entries 64..75; 75 is pad).
        {
            v4f w; w.x = ma.x; w.y = mb.x; w.z = ma.y; w.w = mb.y;
            *(v4f*)&st[2 * l] = w;
            if (l < 6) {
                v4f wh; wh.x = ha.x; wh.y = hb.x; wh.z = ha.y; wh.w = hb.y;
                *(v4f*)&st[64 + 2 * l] = wh;
            }
        }
        __asm__ __volatile__("" ::: "memory");   // writes complete before reads

        // 2. Prefetch next h-row (r = y0 + step - 4); independent of step.
        LOADROW(y0 + step - 4);

        // 3. Horizontal 11-tap for BOTH columns. Window: entries 2l+1..2l+12
        //    (12 values, 10 shared between A and B).
        v2 m1  = st[2 * l + 1];
        v4f r1 = *(const v4f*)&st[2 * l + 2];
        v4f r2 = *(const v4f*)&st[2 * l + 4];
        v4f r3 = *(const v4f*)&st[2 * l + 6];
        v4f r4 = *(const v4f*)&st[2 * l + 8];
        v4f r5 = *(const v4f*)&st[2 * l + 10];
        v2 m12 = st[2 * l + 12];
        v2 m2  = {r1.x, r1.y}, m3  = {r1.z, r1.w};
        v2 m4  = {r2.x, r2.y}, m5  = {r2.z, r2.w};
        v2 m6  = {r3.x, r3.y}, m7  = {r3.z, r3.w};
        v2 m8  = {r4.x, r4.y}, m9  = {r4.z, r4.w};
        v2 m10 = {r5.x, r5.y}, m11 = {r5.z, r5.w};

        // Column A (col c0h+2l): taps m1..m11, weights wg(0..10).
        v2 hmmA = m1 * wg(0);
        v2 hssA = hmmA * m1;
        float hm12A = hmmA.x * m1.y;
        HT_A(m2, 1); HT_A(m3, 2); HT_A(m4, 3); HT_A(m5, 4); HT_A(m6, 5);
        HT_A(m7, 6); HT_A(m8, 7); HT_A(m9, 8); HT_A(m10, 9); HT_A(m11, 10);
        // Column B (col c0h+2l+1): taps m2..m12, weights wg(0..10).
        v2 hmmB = m2 * wg(0);
        v2 hssB = hmmB * m2;
        float hm12B = hmmB.x * m2.y;
        HT_B(m3, 1); HT_B(m4, 2); HT_B(m5, 3); HT_B(m6, 4); HT_B(m7, 5);
        HT_B(m8, 6); HT_B(m9, 7); HT_B(m10, 8); HT_B(m11, 9); HT_B(m12, 10);
        __asm__ __volatile__("" ::: "memory");   // next writes stay after reads

        // 4. Accumulate into the 10 in-flight output rows (slot 9 weight
        //    wg(1); the would-be slot-10 ACCI is folded into the fresh slot).
        ACCI(0); ACCI(1); ACCI(2); ACCI(3); ACCI(4);
        ACCI(5); ACCI(6); ACCI(7); ACCI(8); ACCI(9);

        // 5. Retire output row yy (slot 0 complete, both columns).
        if (yy >= 0) {
            lsum += ssim_retire(PA0.x, PA0.y, QA0.x, QA0.y, EA0);
            lsum += ssim_retire(PB0.x, PB0.y, QB0.x, QB0.y, EB0);
        }

        // 6. Shift ring; fresh slot 9 enters as direct product (weight wg(0)).
        SHIFT(0, 1); SHIFT(1, 2); SHIFT(2, 3); SHIFT(3, 4); SHIFT(4, 5);
        SHIFT(5, 6); SHIFT(6, 7); SHIFT(7, 8); SHIFT(8, 9);
        PA9 = hmmA * wg(0); QA9 = hssA * wg(0); EA9 = hm12A * wg(0);
        PB9 = hmmB * wg(0); QB9 = hssB * wg(0); EB9 = hm12B * wg(0);
    }

    // Reduction: wave shuffle -> one atomic per (single-wave) block.
#pragma unroll
    for (int off = 32; off > 0; off >>= 1) lsum += __shfl_down(lsum, off);
    if (lane == 0) atomicAdd(out, lsum * (0.5f / (float)NPIX));
}

extern "C" void kernel_launch(void* const* d_in, const int* in_sizes, int n_in,
                              void* d_out, int out_size, void* d_ws, size_t ws_size,
                              hipStream_t stream) {
    const float* img1 = (const float*)d_in[0];
    const float* img2 = (const float*)d_in[1];
    float* out = (float*)d_out;

    hipMemsetAsync(out, 0, sizeof(float), stream);

    // 4 strip-pairs x 8 chunks x 48 planes = 1536 single-wave blocks = 6/CU.
    ssim_kernel<<<dim3(4 * 8 * BATCH * CHAN), 64, 0, stream>>>(img1, img2, out);
}

// Round 8
// 153.083 us; speedup vs baseline: 1.0825x; 1.0825x over previous
//
#include <hip/hip_runtime.h>

// SSIM loss v15: v12 + double-buffered LDS row staging (single-variable test).
// Occupancy curve now mapped: 1.5 w/SIMD starves (v14: 888 cyc/output),
// 3 saturates (v12: 730), 6 adds nothing (v9). 2-col/lane closed (needs
// 128 cols/wave -> either CH_H=32 halo tax (v13) or 1.5 w/SIMD (v14)).
// Remaining target: v12's 306 stall cyc/step. Untested serialization: the
// SINGLE row buffer forces each step's ds_write to drain the previous
// step's 11 ds_reads (lgkmcnt(0)) -> exposed LDS round-trip every step,
// hit by all 3 waves in near-lockstep. v11 double-buffered but confounded
// with a staging rewrite. v15: byte-identical v12 body; only change is
// sp[4][80] -> sp[4][2][80] with COMPILE-TIME parity (sb x 37 outer,
// j in {0,1} unrolled inner), so buffer-B writes never wait on buffer-A
// reads and ds offsets stay immediates.
// Predicted: VALUBusy 58->66-72%, kernel 67.5->57-61us if write-drain was
// the stall; +-2% => residual stall is intrinsic, ~ceiling for structure.

#define BATCH  16
#define CHAN   3
#define H_     512
#define W_     512
#define HW     (H_ * W_)
#define CH_H   64
#define NPIX   ((long)BATCH*CHAN*H_*W_)

// Normalized 11-tap Gaussian, sigma=1.5 (constants gave absmax 0 in v1/v2/v6).
#define GW0 0.0010284f
#define GW1 0.0075988f
#define GW2 0.0360008f
#define GW3 0.1093554f
#define GW4 0.2130056f
#define GW5 0.2660117f

typedef float v2 __attribute__((ext_vector_type(2)));

__device__ __forceinline__ float wg(int k) {  // k literal -> folds to constant
    return (k == 0 || k == 10) ? GW0
         : (k == 1 || k == 9)  ? GW1
         : (k == 2 || k == 8)  ? GW2
         : (k == 3 || k == 7)  ? GW3
         : (k == 4 || k == 6)  ? GW4 : GW5;
}

__device__ __forceinline__ v2 pfma(v2 a, v2 b, v2 c) {
#if __has_builtin(__builtin_elementwise_fma)
    return __builtin_elementwise_fma(a, b, c);
#else
    v2 r; r.x = fmaf(a.x, b.x, c.x); r.y = fmaf(a.y, b.y, c.y); return r;
#endif
}
__device__ __forceinline__ v2 psfma(float s, v2 b, v2 c) {  // (s,s)*b + c
    v2 sv; sv.x = s; sv.y = s;
    return pfma(sv, b, c);
}

__device__ __forceinline__ float ssim_retire(float mu1, float mu2,
                                             float x11, float x22, float x12) {
    const float c1 = 1.0e-4f;
    const float c2 = 9.0e-4f;
    float mu1s = mu1 * mu1;
    float mu2s = mu2 * mu2;
    float m12  = mu1 * mu2;
    float num  = (2.0f * m12 + c1) * (2.0f * (x12 - m12) + c2);
    float den  = (mu1s + mu2s + c1) * ((x11 - mu1s) + (x22 - mu2s) + c2);
#if __has_builtin(__builtin_amdgcn_rcpf)
    float l = 1.0f - num * __builtin_amdgcn_rcpf(den);   // v_rcp_f32, ~1 ulp
#else
    float l = 1.0f - num / den;
#endif
    return fminf(fmaxf(l, 0.0f), 1.0f);
}

// Slot i state: P=(mu1,mu2) packed, Q=(x11,x22) packed, E=x12 scalar.
#define DECL(i) v2 P##i = {0.f, 0.f}, Q##i = {0.f, 0.f}; float E##i = 0.f
#define ACCI(i) do { const float wj_ = wg(10 - (i));             \
    P##i = psfma(wj_, hmm, P##i);                                \
    Q##i = psfma(wj_, hss, Q##i);                                \
    E##i = fmaf(wj_, hm12, E##i); } while (0)
#define SHIFT(i, j) P##i = P##j; Q##i = Q##j; E##i = E##j

__global__ __launch_bounds__(256, 3) void ssim_kernel(const float* __restrict__ img1,
                                                      const float* __restrict__ img2,
                                                      float* __restrict__ out) {
    // Double-buffered per-wave staging: 2 x 80 interleaved (img1,img2) pairs.
    __shared__ __align__(16) v2 sp[4][2][80];   // 75 used per buffer
    __shared__ float wsum[4];

    const int tid  = threadIdx.x;
    const int lane = tid & 63;
    const int wv   = tid >> 6;

    const int wid   = blockIdx.x * 4 + wv;     // 0..3071
    const int plane = wid >> 6;
    const int rem   = wid & 63;
    const int strip = rem & 7;
    const int chunk = rem >> 3;
    const int y0 = chunk * CH_H;
    const int c0 = strip * 64;

    // st[par][i] <-> cols c0-5+i of (img1, img2), i = 0..74.
    const int  colg  = c0 - 5 + lane;          // only <0 can be OOB (max 507)
    const bool colOk = (colg >= 0);
    const int  colC  = colOk ? colg : 0;
    const int  colg2  = c0 + 59 + lane;        // halo cols, lanes 0..10
    const bool colOk2 = (lane < 11) && (colg2 < W_);
    const int  col2C  = colOk2 ? colg2 : 0;

    const size_t pb = (size_t)plane * HW;
    const float* __restrict__ p1  = img1 + pb + colC;
    const float* __restrict__ p2  = img2 + pb + colC;
    const float* __restrict__ p1b = img1 + pb + col2C;
    const float* __restrict__ p2b = img2 + pb + col2C;

    v2 (*st)[80] = sp[wv];

    DECL(0); DECL(1); DECL(2); DECL(3); DECL(4); DECL(5);
    DECL(6); DECL(7); DECL(8); DECL(9); DECL(10);
    float lsum = 0.0f;

    // Preload first h-row (r = y0 - 5; zero if OOB -> matches zero padding).
    float cv1, cv2, cv1b, cv2b;
    {
        int r = y0 - 5;
        bool rok = (unsigned)r < (unsigned)H_;
        size_t off = (size_t)(rok ? r : 0) * W_;
        cv1  = (rok && colOk)  ? p1[off]  : 0.0f;
        cv2  = (rok && colOk)  ? p2[off]  : 0.0f;
        cv1b = (rok && colOk2) ? p1b[off] : 0.0f;
        cv2b = (rok && colOk2) ? p2b[off] : 0.0f;
    }

#pragma unroll 1
    for (int sb = 0; sb < 37; ++sb) {
#pragma unroll
        for (int j = 0; j < 2; ++j) {
            const int step = sb * 2 + j;
            const int par  = j;                // compile-time buffer parity
            const int yy = step - 10;          // output row retired this step

            // 1. Stage current h-row into buffer `par` (75 col-pairs).
            //    Writes to par never wait on reads from par^1 (the drain
            //    that serialized v12's single-buffer step).
            {
                v2 v; v.x = cv1; v.y = cv2;
                st[par][lane] = v;
                if (lane < 11) { v2 vb; vb.x = cv1b; vb.y = cv2b; st[par][64 + lane] = vb; }
            }
            __asm__ __volatile__("" ::: "memory");   // writes before reads

            // 2. Prefetch next h-row (r = y0 + yy + 6); independent of step.
            {
                int r = y0 + yy + 6;
                bool rok = (unsigned)r < (unsigned)H_;
                size_t off = (size_t)(rok ? r : 0) * W_;
                cv1  = (rok && colOk)  ? p1[off]  : 0.0f;
                cv2  = (rok && colOk)  ? p2[off]  : 0.0f;
                cv1b = (rok && colOk2) ? p1b[off] : 0.0f;
                cv2b = (rok && colOk2) ? p2b[off] : 0.0f;
            }

            // 3. Horizontal 11-tap, packed: hmm=(m1,m2), hss=(m11,m22), hm12.
            v2 hmm = {0.f, 0.f}, hss = {0.f, 0.f};
            float hm12 = 0.f;
#pragma unroll
            for (int k = 0; k < 11; ++k) {
                v2 ab = st[par][lane + k];     // ds_read_b64, imm offset
                float wk = wg(k);
                v2 t = ab;
                t.x *= wk; t.y *= wk;          // pk_mul (t1,t2)
                hmm += t;                      // pk_add
                hss = pfma(t, ab, hss);        // pk_fma -> (m11,m22)
                hm12 = fmaf(t.x, ab.y, hm12);  // scalar cross term
            }
            __asm__ __volatile__("" ::: "memory");   // iter j+2 writes stay after these reads

            // 4. Accumulate into the 11 in-flight output rows.
            ACCI(0); ACCI(1); ACCI(2); ACCI(3); ACCI(4); ACCI(5);
            ACCI(6); ACCI(7); ACCI(8); ACCI(9); ACCI(10);

            // 5. Retire output row yy (slot 0 complete).
            if (yy >= 0) lsum += ssim_retire(P0.x, P0.y, Q0.x, Q0.y, E0);

            // 6. Shift the register ring (pure SSA renames; unroll elides half).
            SHIFT(0, 1); SHIFT(1, 2); SHIFT(2, 3); SHIFT(3, 4); SHIFT(4, 5);
            SHIFT(5, 6); SHIFT(6, 7); SHIFT(7, 8); SHIFT(8, 9); SHIFT(9, 10);
            P10 = (v2){0.f, 0.f}; Q10 = (v2){0.f, 0.f}; E10 = 0.f;
        }
    }

    // Reduction: wave shuffle -> LDS -> one atomic per block.
#pragma unroll
    for (int off = 32; off > 0; off >>= 1) lsum += __shfl_down(lsum, off);
    if (lane == 0) wsum[wv] = lsum;
    __syncthreads();
    if (tid == 0) {
        float bs = wsum[0] + wsum[1] + wsum[2] + wsum[3];
        atomicAdd(out, bs * (0.5f / (float)NPIX));
    }
}

extern "C" void kernel_launch(void* const* d_in, const int* in_sizes, int n_in,
                              void* d_out, int out_size, void* d_ws, size_t ws_size,
                              hipStream_t stream) {
    const float* img1 = (const float*)d_in[0];
    const float* img2 = (const float*)d_in[1];
    float* out = (float*)d_out;

    hipMemsetAsync(out, 0, sizeof(float), stream);

    // 8 strips x 8 chunks x 48 planes = 3072 waves = 768 blocks = 3/CU.
    ssim_kernel<<<dim3(8 * 8 * BATCH * CHAN / 4), 256, 0, stream>>>(img1, img2, out);
}